// Round 11
// baseline (3727.003 us; speedup 1.0000x reference)
//
#include <hip/hip_runtime.h>
#include <hip/hip_fp16.h>

#define BN_EPS 1e-5f
#define CHUNK 8192            // edges per bucketing block (hist and scatter must match)
#define BBITS 7               // 128 nodes per bucket

typedef _Float16 half8 __attribute__((ext_vector_type(8)));
typedef float f32x4 __attribute__((ext_vector_type(4)));

__device__ __forceinline__ float4 f4zero() { return make_float4(0.f, 0.f, 0.f, 0.f); }

// ---------------- bucket-sort edge grouping (LDS-scope atomics only) ----------------

__global__ __launch_bounds__(256) void k_bucket_hist(const int* __restrict__ dst,
                                                     int* __restrict__ tableT,
                                                     int nA, int nbuck, int e) {
    __shared__ int h[1024];
    int blk = blockIdx.x, tid = threadIdx.x;
    for (int k = tid; k < 1024; k += 256) h[k] = 0;
    __syncthreads();
    int base = blk * CHUNK;
    if (base + CHUNK <= e && (e & 3) == 0) {
        const int4* d4 = (const int4*)(dst + base);
#pragma unroll
        for (int t = 0; t < CHUNK / 1024; ++t) {
            int4 d = d4[t * 256 + tid];
            atomicAdd(&h[d.x >> BBITS], 1);
            atomicAdd(&h[d.y >> BBITS], 1);
            atomicAdd(&h[d.z >> BBITS], 1);
            atomicAdd(&h[d.w >> BBITS], 1);
        }
    } else {
        for (int i = base + tid; i < e && i < base + CHUNK; i += 256)
            atomicAdd(&h[dst[i] >> BBITS], 1);
    }
    __syncthreads();
    for (int k = tid; k < nbuck; k += 256)
        tableT[(size_t)k * nA + blk] = h[k];
}

// scatter packed edge word (src<<7 | dst&127) into bucket-grouped order
__global__ __launch_bounds__(256) void k_bucket_scatter(const int* __restrict__ src,
                                                        const int* __restrict__ dst,
                                                        const int* __restrict__ tableT,
                                                        int* __restrict__ bedp,
                                                        int nA, int nbuck, int e) {
    __shared__ int cur[1024];
    int blk = blockIdx.x, tid = threadIdx.x;
    for (int k = tid; k < nbuck; k += 256)
        cur[k] = tableT[(size_t)k * nA + blk];
    __syncthreads();
    int base = blk * CHUNK;
    if (base + CHUNK <= e && (e & 3) == 0) {
        const int4* s4 = (const int4*)(src + base);
        const int4* d4 = (const int4*)(dst + base);
#pragma unroll
        for (int t = 0; t < CHUNK / 1024; ++t) {
            int4 s = s4[t * 256 + tid];
            int4 d = d4[t * 256 + tid];
            int p0 = atomicAdd(&cur[d.x >> BBITS], 1); bedp[p0] = (s.x << BBITS) | (d.x & 127);
            int p1 = atomicAdd(&cur[d.y >> BBITS], 1); bedp[p1] = (s.y << BBITS) | (d.y & 127);
            int p2 = atomicAdd(&cur[d.z >> BBITS], 1); bedp[p2] = (s.z << BBITS) | (d.z & 127);
            int p3 = atomicAdd(&cur[d.w >> BBITS], 1); bedp[p3] = (s.w << BBITS) | (d.w & 127);
        }
    } else {
        for (int i = base + tid; i < e && i < base + CHUNK; i += 256) {
            int d = dst[i];
            int p = atomicAdd(&cur[d >> BBITS], 1);
            bedp[p] = (src[i] << BBITS) | (d & 127);
        }
    }
}

// per-bucket degree count -> dinv (needed by GEMM1's folded scaling)
__global__ __launch_bounds__(256) void k_bucket_count(const int* __restrict__ bedp,
                                                      const int* __restrict__ tableT,
                                                      float* __restrict__ dinv,
                                                      int nA, int nbuck, int n, int e) {
    __shared__ int lcnt[128];
    int b = blockIdx.x, tid = threadIdx.x;
    if (tid < 128) lcnt[tid] = 0;
    __syncthreads();
    int start = tableT[(size_t)b * nA];
    int end = (b + 1 < nbuck) ? tableT[(size_t)(b + 1) * nA] : e;
    for (int i = start + tid; i < end; i += 256)
        atomicAdd(&lcnt[bedp[i] & 127], 1);
    __syncthreads();
    if (tid < 128) {
        int node = (b << BBITS) + tid;
        if (node < n) dinv[node] = rsqrtf((float)(lcnt[tid] + 1));
    }
}

// exclusive scan over tableT (flattened [bucket][chunk])
__global__ __launch_bounds__(1024) void k_scan_block(const int* __restrict__ in,
                                                     int* __restrict__ outp,
                                                     int* __restrict__ partials, int len) {
    __shared__ int s[1024];
    int t = threadIdx.x;
    int gid = blockIdx.x * 1024 + t;
    int v = (gid < len) ? in[gid] : 0;
    int x = v;
    s[t] = x;
    __syncthreads();
    for (int d = 1; d < 1024; d <<= 1) {
        int y = (t >= d) ? s[t - d] : 0;
        __syncthreads();
        x += y;
        s[t] = x;
        __syncthreads();
    }
    if (gid < len) outp[gid] = x - v;
    if (t == 1023) partials[blockIdx.x] = x;
}

__global__ __launch_bounds__(1024) void k_scan_partials(int* __restrict__ partials, int nb) {
    __shared__ int s[1024];
    int t = threadIdx.x;
    int v = (t < nb) ? partials[t] : 0;
    int x = v;
    s[t] = x;
    __syncthreads();
    for (int d = 1; d < 1024; d <<= 1) {
        int y = (t >= d) ? s[t - d] : 0;
        __syncthreads();
        x += y;
        s[t] = x;
        __syncthreads();
    }
    if (t < nb) partials[t] = x - v;
    if (t == nb - 1) partials[nb] = x;
}

__global__ __launch_bounds__(256) void k_scan_add(int* __restrict__ offs,
                                                  const int* __restrict__ partials, int len) {
    int gid = blockIdx.x * 256 + threadIdx.x;
    if (gid < len) offs[gid] += partials[gid >> 10];
    if (gid == 0) offs[len] = partials[(len + 1023) >> 10];
}

// ---------------- W pre-pack (all 3 layers in one launch): f32 -> f16 B-fragment order ----

__global__ __launch_bounds__(256) void k_packW3(const float* __restrict__ W1,
                                                const float* __restrict__ W2,
                                                const float* __restrict__ W3,
                                                _Float16* __restrict__ out) {
    int t = blockIdx.x * 256 + threadIdx.x;     // 0..6143
    if (t >= 6144) return;
    int wi = t >> 11;
    int tt = t & 2047;
    const float* W = (wi == 0) ? W1 : ((wi == 1) ? W2 : W3);
    int kc = tt >> 9;
    int rem = tt & 511;
    int ct = rem >> 6;
    int lane = rem & 63;
    int q = lane >> 4;
    int col = ct * 16 + (lane & 15);
    half8 h;
#pragma unroll
    for (int j = 0; j < 8; ++j)
        h[j] = (_Float16)W[(kc * 32 + q * 8 + j) * 128 + col];
    *(half8*)(out + (size_t)t * 8) = h;
}

// ---------------- MFMA GEMM: C[n,128](f16, row-major) = (A @ W) * dinv[row] ----------------
// (R8-verified structure)

template <bool AF32>
__global__ __launch_bounds__(256) void k_gemm_mfma(const void* __restrict__ Av,
                                                   const _Float16* __restrict__ pW,
                                                   const float* __restrict__ dinv,
                                                   uint4* __restrict__ C, int n) {
    __shared__ char smem[32768];
    uint4* sW = (uint4*)smem;
    int tid = threadIdx.x;

    {
        const uint4* gW = (const uint4*)pW;
#pragma unroll
        for (int i = 0; i < 8; ++i) sW[tid + 256 * i] = gW[tid + 256 * i];
    }
    __syncthreads();

    int wave = tid >> 6, lane = tid & 63;
    int quad = lane >> 4, l16 = lane & 15;
    int row0 = blockIdx.x * 64 + wave * 16;
    int arow = row0 + l16;
    int arowc = (arow < n) ? arow : (n - 1);

    half8 af[4];
    if (AF32) {
        const float* A = (const float*)Av + (size_t)arowc * 128 + quad * 8;
#pragma unroll
        for (int kc = 0; kc < 4; ++kc) {
            float4 lo = *(const float4*)(A + kc * 32);
            float4 hi = *(const float4*)(A + kc * 32 + 4);
            half8 h;
            h[0] = (_Float16)lo.x; h[1] = (_Float16)lo.y;
            h[2] = (_Float16)lo.z; h[3] = (_Float16)lo.w;
            h[4] = (_Float16)hi.x; h[5] = (_Float16)hi.y;
            h[6] = (_Float16)hi.z; h[7] = (_Float16)hi.w;
            af[kc] = h;
        }
    } else {
        const _Float16* A = (const _Float16*)Av + (size_t)arowc * 128 + quad * 8;
#pragma unroll
        for (int kc = 0; kc < 4; ++kc)
            af[kc] = *(const half8*)(A + kc * 32);
    }

    f32x4 acc[8];
#pragma unroll
    for (int ct = 0; ct < 8; ++ct) acc[ct] = (f32x4){0.f, 0.f, 0.f, 0.f};

#pragma unroll
    for (int kc = 0; kc < 4; ++kc) {
#pragma unroll
        for (int ct = 0; ct < 8; ++ct) {
            half8 bf = *(half8*)&sW[(kc * 8 + ct) * 64 + lane];
            acc[ct] = __builtin_amdgcn_mfma_f32_16x16x32_f16(af[kc], bf, acc[ct], 0, 0, 0);
        }
    }

    __syncthreads();

    _Float16* eb = (_Float16*)smem + wave * 16 * 136;   // 136 halfs = 272 B row stride
    float dv[4];
#pragma unroll
    for (int r = 0; r < 4; ++r) {
        int rr = row0 + quad * 4 + r;
        dv[r] = dinv[(rr < n) ? rr : (n - 1)];
    }
#pragma unroll
    for (int ct = 0; ct < 8; ++ct)
#pragma unroll
        for (int r = 0; r < 4; ++r)
            eb[(quad * 4 + r) * 136 + ct * 16 + l16] = (_Float16)(acc[ct][r] * dv[r]);

#pragma unroll
    for (int i = 0; i < 4; ++i) {
        int linear = i * 64 + lane;
        int r = linear >> 4, c = linear & 15;
        uint4 v = *(uint4*)((char*)eb + r * 272 + c * 16);
        int row = row0 + r;
        if (row < n) C[(size_t)row * 16 + c] = v;
    }
}

// ---------------- bucketed LDS-accumulate aggregation + bias + ReLU + BN ----------------
// grid (nbuck, 2): one block per (bucket, feature-half). LDS f32 accum 128x65.
// Edge loop: 16 slots x batch-8; gather = 16 lanes x 8 B = 128 B half-row; ds_add_f32.
// Epilogue: +self row, *dinv, BN; layer 3 fuses the 2-class classifier.

__device__ __forceinline__ void lds_add4(float* p, uint2 q) {
    float2 fa = __half22float2(*(__half2*)&q.x);
    float2 fb = __half22float2(*(__half2*)&q.y);
    atomicAdd(p + 0, fa.x);
    atomicAdd(p + 1, fa.y);
    atomicAdd(p + 2, fb.x);
    atomicAdd(p + 3, fb.y);
}

template <bool FUSE_CLS>
__global__ __launch_bounds__(256) void k_agg_lds(const uint2* __restrict__ A,
                                                 const int* __restrict__ bedp,
                                                 const int* __restrict__ tableT,
                                                 const float* __restrict__ dinv,
                                                 const float* __restrict__ bias,
                                                 const float* __restrict__ g,
                                                 const float* __restrict__ be,
                                                 const float* __restrict__ rm,
                                                 const float* __restrict__ rv,
                                                 uint2* __restrict__ Hout,
                                                 const float* __restrict__ Wc,
                                                 float2* __restrict__ partials,
                                                 int nA, int nbuck, int n, int e) {
    __shared__ float acc[128 * 65];    // node stride 65 floats (bank decorrelation)
    int b = blockIdx.x, y = blockIdx.y, tid = threadIdx.x;
    for (int i = tid; i < 128 * 65; i += 256) acc[i] = 0.f;
    __syncthreads();

    int start = tableT[(size_t)b * nA];
    int end = (b + 1 < nbuck) ? tableT[(size_t)(b + 1) * nA] : e;

    int g16 = tid >> 4, l16 = tid & 15;
    int abase = y * 16 + l16;          // uint2 offset within the 32-uint2 row

    for (int base = start; base < end; base += 128) {   // 16 slots x batch 8
        int idx[8], w[8];
        uint2 q[8];
#pragma unroll
        for (int j = 0; j < 8; ++j) {
            idx[j] = base + j * 16 + g16;
            w[j] = (idx[j] < end) ? bedp[idx[j]] : -1;
        }
#pragma unroll
        for (int j = 0; j < 8; ++j)
            if (w[j] >= 0) q[j] = A[((size_t)(w[j] >> BBITS)) * 32 + abase];
#pragma unroll
        for (int j = 0; j < 8; ++j)
            if (w[j] >= 0) lds_add4(&acc[(w[j] & 127) * 65 + l16 * 4], q[j]);
    }
    __syncthreads();

    // epilogue: 2 threads per node, 32 features each
    int nd = tid >> 1, h32 = tid & 1;
    int node = (b << BBITS) + nd;
    if (node >= n) return;
    float di = dinv[node];
    const uint2* selfp = A + (size_t)node * 32 + y * 16 + h32 * 8;
    const float4* b4 = (const float4*)bias;
    const float4* g4 = (const float4*)g;
    const float4* e4 = (const float4*)be;
    const float4* m4 = (const float4*)rm;
    const float4* v4 = (const float4*)rv;
    int pbase = y * 16 + h32 * 8;      // float4 index over 128 features
    float cls0 = 0.f, cls1 = 0.f;
    uint2 outw[8];
#pragma unroll
    for (int u = 0; u < 8; ++u) {
        uint2 qs = selfp[u];
        float2 fa = __half22float2(*(__half2*)&qs.x);
        float2 fb = __half22float2(*(__half2*)&qs.y);
        float* ap = &acc[nd * 65 + h32 * 32 + u * 4];
        float s0 = (ap[0] + fa.x) * di;
        float s1 = (ap[1] + fa.y) * di;
        float s2 = (ap[2] + fb.x) * di;
        float s3 = (ap[3] + fb.y) * di;
        float4 bb = b4[pbase + u], gg = g4[pbase + u], ee = e4[pbase + u];
        float4 mm = m4[pbase + u], vv = v4[pbase + u];
        float t0, o0, o1, o2, o3;
        t0 = fmaxf(s0 + bb.x, 0.f); o0 = (t0 - mm.x) * rsqrtf(vv.x + BN_EPS) * gg.x + ee.x;
        t0 = fmaxf(s1 + bb.y, 0.f); o1 = (t0 - mm.y) * rsqrtf(vv.y + BN_EPS) * gg.y + ee.y;
        t0 = fmaxf(s2 + bb.z, 0.f); o2 = (t0 - mm.z) * rsqrtf(vv.z + BN_EPS) * gg.z + ee.z;
        t0 = fmaxf(s3 + bb.w, 0.f); o3 = (t0 - mm.w) * rsqrtf(vv.w + BN_EPS) * gg.w + ee.w;
        if (FUSE_CLS) {
            const float4* Wv = (const float4*)Wc;    // [128][2] row-major
            float4 wA = Wv[(pbase + u) * 2];
            float4 wB = Wv[(pbase + u) * 2 + 1];
            cls0 += o0 * wA.x + o1 * wA.z + o2 * wB.x + o3 * wB.z;
            cls1 += o0 * wA.y + o1 * wA.w + o2 * wB.y + o3 * wB.w;
        } else {
            __half2 pa = __floats2half2_rn(o0, o1);
            __half2 pb = __floats2half2_rn(o2, o3);
            outw[u].x = *(unsigned int*)&pa;
            outw[u].y = *(unsigned int*)&pb;
        }
    }
    if (!FUSE_CLS) {
        uint2* hp = Hout + (size_t)node * 32 + y * 16 + h32 * 8;
#pragma unroll
        for (int u = 0; u < 8; ++u) hp[u] = outw[u];
    } else {
        cls0 += __shfl_xor(cls0, 1);
        cls1 += __shfl_xor(cls1, 1);
        if (h32 == 0) partials[(size_t)y * n + node] = make_float2(cls0, cls1);
    }
}

__global__ __launch_bounds__(256) void k_reduce_out(const float2* __restrict__ partials,
                                                    const float* __restrict__ bc,
                                                    float2* __restrict__ out2, int n) {
    int i = blockIdx.x * 256 + threadIdx.x;
    if (i >= n) return;
    float2 p0 = partials[i];
    float2 p1 = partials[(size_t)n + i];
    out2[i] = make_float2(p0.x + p1.x + bc[0], p0.y + p1.y + bc[1]);
}

// ---------------- launch ----------------

extern "C" void kernel_launch(void* const* d_in, const int* in_sizes, int n_in,
                              void* d_out, int out_size, void* d_ws, size_t ws_size,
                              hipStream_t stream) {
    const float* x   = (const float*)d_in[0];
    const int*   ei  = (const int*)d_in[1];
    const float* W1  = (const float*)d_in[2];
    const float* b1  = (const float*)d_in[3];
    const float* W2  = (const float*)d_in[4];
    const float* b2  = (const float*)d_in[5];
    const float* W3  = (const float*)d_in[6];
    const float* b3  = (const float*)d_in[7];
    const float* g1  = (const float*)d_in[8];
    const float* be1 = (const float*)d_in[9];
    const float* rm1 = (const float*)d_in[10];
    const float* rv1 = (const float*)d_in[11];
    const float* g2  = (const float*)d_in[12];
    const float* be2 = (const float*)d_in[13];
    const float* rm2 = (const float*)d_in[14];
    const float* rv2 = (const float*)d_in[15];
    const float* g3  = (const float*)d_in[16];
    const float* be3 = (const float*)d_in[17];
    const float* rm3 = (const float*)d_in[18];
    const float* rv3 = (const float*)d_in[19];
    const float* Wc  = (const float*)d_in[20];
    const float* bc  = (const float*)d_in[21];
    float* out = (float*)d_out;

    int n = in_sizes[0] / 128;
    int e = in_sizes[1] / 2;
    const int* src = ei;
    const int* dst = ei + e;

    char* ws = (char*)d_ws;
    size_t off = 0;
    auto alloc = [&](size_t bytes) -> char* {
        char* p = ws + off;
        off += (bytes + 255) & ~(size_t)255;
        return p;
    };
    int nA    = (e + CHUNK - 1) / CHUNK;
    int nbuck = (n + (1 << BBITS) - 1) >> BBITS;
    int tlen  = nbuck * nA;

    char*      bufA   = (char*) alloc((size_t)n * 128 * 2);        // GEMM out f16 row-major
    char*      bufH   = (char*) alloc((size_t)n * 128 * 2);        // H f16 / partials alias
    float*     dinv   = (float*)alloc((size_t)n * 4);
    int*       bedp   = (int*)  alloc((size_t)e * 4);              // packed bucket-grouped edges
    int*       tableT = (int*)  alloc((size_t)(tlen + 1) * 4);
    int*       parts  = (int*)  alloc(8192);
    _Float16*  pW     = (_Float16*)alloc(3 * 16384 * 2);
    (void)ws_size; (void)n_in; (void)out_size;

    int nbT = (tlen + 1023) / 1024;

    k_packW3<<<24, 256, 0, stream>>>(W1, W2, W3, pW);
    k_bucket_hist<<<nA, 256, 0, stream>>>(dst, tableT, nA, nbuck, e);
    k_scan_block<<<nbT, 1024, 0, stream>>>(tableT, tableT, parts, tlen);
    k_scan_partials<<<1, 1024, 0, stream>>>(parts, nbT);
    k_scan_add<<<(tlen + 255) / 256, 256, 0, stream>>>(tableT, parts, tlen);
    k_bucket_scatter<<<nA, 256, 0, stream>>>(src, dst, tableT, bedp, nA, nbuck, e);
    k_bucket_count<<<nbuck, 256, 0, stream>>>(bedp, tableT, dinv, nA, nbuck, n, e);

    int gGemm = (n + 63) / 64;
    dim3 gAgg(nbuck, 2);

    k_gemm_mfma<true><<<gGemm, 256, 0, stream>>>(x, pW, dinv, (uint4*)bufA, n);
    k_agg_lds<false><<<gAgg, 256, 0, stream>>>((const uint2*)bufA, bedp, tableT, dinv,
                                               b1, g1, be1, rm1, rv1, (uint2*)bufH,
                                               nullptr, nullptr, nA, nbuck, n, e);

    k_gemm_mfma<false><<<gGemm, 256, 0, stream>>>(bufH, pW + 16384, dinv, (uint4*)bufA, n);
    k_agg_lds<false><<<gAgg, 256, 0, stream>>>((const uint2*)bufA, bedp, tableT, dinv,
                                               b2, g2, be2, rm2, rv2, (uint2*)bufH,
                                               nullptr, nullptr, nA, nbuck, n, e);

    k_gemm_mfma<false><<<gGemm, 256, 0, stream>>>(bufH, pW + 32768, dinv, (uint4*)bufA, n);
    float2* partials = (float2*)bufH;   // H dead after gemm3 consumed it
    k_agg_lds<true><<<gAgg, 256, 0, stream>>>((const uint2*)bufA, bedp, tableT, dinv,
                                              b3, g3, be3, rm3, rv3, nullptr,
                                              Wc, partials, nA, nbuck, n, e);
    k_reduce_out<<<(n + 255) / 256, 256, 0, stream>>>(partials, bc, (float2*)out, n);
}

// Round 12
// 394.717 us; speedup vs baseline: 9.4422x; 9.4422x over previous
//
#include <hip/hip_runtime.h>
#include <hip/hip_fp16.h>

#define BN_EPS 1e-5f
#define CHUNK 4096            // edges per bucketing block (hist and scatter must match)
#define BBITS 7               // 128 nodes per bucket

typedef _Float16 half8 __attribute__((ext_vector_type(8)));
typedef float f32x4 __attribute__((ext_vector_type(4)));

__device__ __forceinline__ float4 f4zero() { return make_float4(0.f, 0.f, 0.f, 0.f); }

// ---------------- K1: packW(all 3) + bucket histogram (blockIdx-split) ----------------

__global__ __launch_bounds__(256) void k_pack_hist(const float* __restrict__ W1,
                                                   const float* __restrict__ W2,
                                                   const float* __restrict__ W3,
                                                   _Float16* __restrict__ pW,
                                                   const int* __restrict__ dst,
                                                   int* __restrict__ tableT,
                                                   int nA, int nbuck, int e) {
    __shared__ int h[1024];
    int tid = threadIdx.x;
    if (blockIdx.x < 24) {            // W pre-pack: f32 [128][128] -> f16 B-fragment order
        int t = blockIdx.x * 256 + tid;   // 0..6143
        int wi = t >> 11;
        int tt = t & 2047;
        const float* W = (wi == 0) ? W1 : ((wi == 1) ? W2 : W3);
        int kc = tt >> 9;
        int rem = tt & 511;
        int ct = rem >> 6;
        int lane = rem & 63;
        int q = lane >> 4;
        int col = ct * 16 + (lane & 15);
        half8 hh;
#pragma unroll
        for (int j = 0; j < 8; ++j)
            hh[j] = (_Float16)W[(kc * 32 + q * 8 + j) * 128 + col];
        *(half8*)(pW + (size_t)t * 8) = hh;
        return;
    }
    int blk = blockIdx.x - 24;
    for (int k = tid; k < 1024; k += 256) h[k] = 0;
    __syncthreads();
    int base = blk * CHUNK;
    if (base + CHUNK <= e && (e & 3) == 0) {
        const int4* d4 = (const int4*)(dst + base);
#pragma unroll
        for (int t = 0; t < CHUNK / 1024; ++t) {
            int4 d = d4[t * 256 + tid];
            atomicAdd(&h[d.x >> BBITS], 1);
            atomicAdd(&h[d.y >> BBITS], 1);
            atomicAdd(&h[d.z >> BBITS], 1);
            atomicAdd(&h[d.w >> BBITS], 1);
        }
    } else {
        for (int i = base + tid; i < e && i < base + CHUNK; i += 256)
            atomicAdd(&h[dst[i] >> BBITS], 1);
    }
    __syncthreads();
    for (int k = tid; k < nbuck; k += 256)
        tableT[(size_t)k * nA + blk] = h[k];
}

// ---------------- K2/K3: 2-op exclusive scan of tableT ----------------

__global__ __launch_bounds__(1024) void k_scan_block(const int* __restrict__ in,
                                                     int* __restrict__ outp,
                                                     int* __restrict__ partials, int len) {
    __shared__ int s[1024];
    int t = threadIdx.x;
    int gid = blockIdx.x * 1024 + t;
    int v = (gid < len) ? in[gid] : 0;
    int x = v;
    s[t] = x;
    __syncthreads();
    for (int d = 1; d < 1024; d <<= 1) {
        int y = (t >= d) ? s[t - d] : 0;
        __syncthreads();
        x += y;
        s[t] = x;
        __syncthreads();
    }
    if (gid < len) outp[gid] = x - v;
    if (t == 1023) partials[blockIdx.x] = x;
}

// each 256-block self-sums the partials it needs (no separate partials-scan kernel)
__global__ __launch_bounds__(256) void k_scan_addp(int* __restrict__ data,
                                                   const int* __restrict__ partials, int len) {
    __shared__ int red[256];
    int tid = threadIdx.x;
    int K = blockIdx.x >> 2;          // number of preceding 1024-segments
    int s = 0;
    for (int t = tid; t < K; t += 256) s += partials[t];
    red[tid] = s;
    __syncthreads();
    for (int d = 128; d > 0; d >>= 1) {
        if (tid < d) red[tid] += red[tid + d];
        __syncthreads();
    }
    int gid = blockIdx.x * 256 + tid;
    if (gid < len) data[gid] += red[0];
}

// ---------------- K4: bucket-grouped COO scatter (LDS cursors) ----------------

__global__ __launch_bounds__(256) void k_bucket_scatter(const int* __restrict__ src,
                                                        const int* __restrict__ dst,
                                                        const int* __restrict__ tableT,
                                                        int2* __restrict__ bed,
                                                        int nA, int nbuck, int e) {
    __shared__ int cur[1024];
    int blk = blockIdx.x, tid = threadIdx.x;
    for (int k = tid; k < nbuck; k += 256)
        cur[k] = tableT[(size_t)k * nA + blk];
    __syncthreads();
    int base = blk * CHUNK;
    if (base + CHUNK <= e && (e & 3) == 0) {
        const int4* s4 = (const int4*)(src + base);
        const int4* d4 = (const int4*)(dst + base);
#pragma unroll
        for (int t = 0; t < CHUNK / 1024; ++t) {
            int4 s = s4[t * 256 + tid];
            int4 d = d4[t * 256 + tid];
            int p0 = atomicAdd(&cur[d.x >> BBITS], 1); bed[p0] = make_int2(s.x, d.x);
            int p1 = atomicAdd(&cur[d.y >> BBITS], 1); bed[p1] = make_int2(s.y, d.y);
            int p2 = atomicAdd(&cur[d.z >> BBITS], 1); bed[p2] = make_int2(s.z, d.z);
            int p3 = atomicAdd(&cur[d.w >> BBITS], 1); bed[p3] = make_int2(s.w, d.w);
        }
    } else {
        for (int i = base + tid; i < e && i < base + CHUNK; i += 256) {
            int d = dst[i];
            int p = atomicAdd(&cur[d >> BBITS], 1);
            bed[p] = make_int2(src[i], d);
        }
    }
}

// ---------------- K5: per-bucket rank + counts + dinv + padded local offsets ----------------

__global__ __launch_bounds__(256) void k_bucket_rank(const int2* __restrict__ bed,
                                                     const int* __restrict__ tableT,
                                                     int* __restrict__ brank,
                                                     int* __restrict__ counts,
                                                     float* __restrict__ dinv,
                                                     int* __restrict__ localOff,
                                                     int* __restrict__ btot,
                                                     int nA, int nbuck, int n, int e) {
    __shared__ int lcnt[128];
    __shared__ int lscan[128];
    int b = blockIdx.x, tid = threadIdx.x;
    if (tid < 128) lcnt[tid] = 0;
    __syncthreads();
    int start = tableT[(size_t)b * nA];
    int end = (b + 1 < nbuck) ? tableT[(size_t)(b + 1) * nA] : e;
    for (int i = start + tid; i < end; i += 256) {
        int2 q = bed[i];
        brank[i] = atomicAdd(&lcnt[q.y & 127], 1);
    }
    __syncthreads();
    int padded = 0;
    if (tid < 128) {
        padded = (lcnt[tid] + 7) & ~7;
        lscan[tid] = padded;
    }
    __syncthreads();
    for (int d = 1; d < 128; d <<= 1) {          // Hillis-Steele inclusive scan over 128
        int y = (tid < 128 && tid >= d) ? lscan[tid - d] : 0;
        __syncthreads();
        if (tid < 128) lscan[tid] += y;
        __syncthreads();
    }
    if (tid < 128) {
        int node = (b << BBITS) + tid;
        if (node < n) {
            int c = lcnt[tid];
            counts[node] = c;
            dinv[node] = rsqrtf((float)(c + 1));
            localOff[node] = lscan[tid] - padded;   // exclusive padded offset within bucket
        }
        if (tid == 127) btot[b] = lscan[127];
    }
}

// ---------------- K6: one-block scan of per-bucket padded totals ----------------

__global__ __launch_bounds__(1024) void k_scan_buckets(const int* __restrict__ btot,
                                                       int* __restrict__ bucketBase, int nbuck) {
    __shared__ int s[1024];
    int t = threadIdx.x;
    int v = (t < nbuck) ? btot[t] : 0;
    int x = v;
    s[t] = x;
    __syncthreads();
    for (int d = 1; d < 1024; d <<= 1) {
        int y = (t >= d) ? s[t - d] : 0;
        __syncthreads();
        x += y;
        s[t] = x;
        __syncthreads();
    }
    if (t < nbuck) bucketBase[t] = x - v;
    if (t == nbuck - 1) bucketBase[nbuck] = x;
}

// ---------------- K7: finalize (blockIdx-split): offs + pad-fill + zero-row | edge place ----

__global__ __launch_bounds__(256) void k_finalize(const int* __restrict__ counts,
                                                  const int* __restrict__ localOff,
                                                  const int* __restrict__ bucketBase,
                                                  int* __restrict__ offs,
                                                  int* __restrict__ er,
                                                  const int2* __restrict__ bed,
                                                  const int* __restrict__ brank,
                                                  unsigned int* __restrict__ bufAzero,
                                                  int n, int e, int gN, int nbuck) {
    int tid = threadIdx.x;
    if (blockIdx.x < gN) {
        int node = blockIdx.x * 256 + tid;
        if (node < n) {
            int c = counts[node];
            int o = bucketBase[node >> BBITS] + localOff[node];
            offs[node] = o;
            int pc = (c + 7) & ~7;
            for (int j = c; j < pc; ++j) er[o + j] = n;   // dummy zero-row index
        }
        if (node == 0) offs[n] = bucketBase[nbuck];
        if (blockIdx.x == 0 && tid < 64) bufAzero[tid] = 0u;  // zero 256 B pad row of bufA
    } else {
        int i = ((blockIdx.x - gN) * 256 + tid) * 2;
        if (i + 1 < e) {
            int4 q = *(const int4*)(bed + i);      // (s0,d0,s1,d1)
            int2 r = *(const int2*)(brank + i);
            er[bucketBase[q.y >> BBITS] + localOff[q.y] + r.x] = q.x;
            er[bucketBase[q.w >> BBITS] + localOff[q.w] + r.y] = q.z;
        } else if (i < e) {
            int2 q = bed[i];
            er[bucketBase[q.y >> BBITS] + localOff[q.y] + brank[i]] = q.x;
        }
    }
}

// ---------------- MFMA GEMM: C[n,128](f16, row-major) = (A @ W) * dinv[row] ----------------
// (R8-verified structure, unchanged)

template <bool AF32>
__global__ __launch_bounds__(256) void k_gemm_mfma(const void* __restrict__ Av,
                                                   const _Float16* __restrict__ pW,
                                                   const float* __restrict__ dinv,
                                                   uint4* __restrict__ C, int n) {
    __shared__ char smem[32768];
    uint4* sW = (uint4*)smem;
    int tid = threadIdx.x;

    {
        const uint4* gW = (const uint4*)pW;
#pragma unroll
        for (int i = 0; i < 8; ++i) sW[tid + 256 * i] = gW[tid + 256 * i];
    }
    __syncthreads();

    int wave = tid >> 6, lane = tid & 63;
    int quad = lane >> 4, l16 = lane & 15;
    int row0 = blockIdx.x * 64 + wave * 16;
    int arow = row0 + l16;
    int arowc = (arow < n) ? arow : (n - 1);

    half8 af[4];
    if (AF32) {
        const float* A = (const float*)Av + (size_t)arowc * 128 + quad * 8;
#pragma unroll
        for (int kc = 0; kc < 4; ++kc) {
            float4 lo = *(const float4*)(A + kc * 32);
            float4 hi = *(const float4*)(A + kc * 32 + 4);
            half8 h;
            h[0] = (_Float16)lo.x; h[1] = (_Float16)lo.y;
            h[2] = (_Float16)lo.z; h[3] = (_Float16)lo.w;
            h[4] = (_Float16)hi.x; h[5] = (_Float16)hi.y;
            h[6] = (_Float16)hi.z; h[7] = (_Float16)hi.w;
            af[kc] = h;
        }
    } else {
        const _Float16* A = (const _Float16*)Av + (size_t)arowc * 128 + quad * 8;
#pragma unroll
        for (int kc = 0; kc < 4; ++kc)
            af[kc] = *(const half8*)(A + kc * 32);
    }

    f32x4 acc[8];
#pragma unroll
    for (int ct = 0; ct < 8; ++ct) acc[ct] = (f32x4){0.f, 0.f, 0.f, 0.f};

#pragma unroll
    for (int kc = 0; kc < 4; ++kc) {
#pragma unroll
        for (int ct = 0; ct < 8; ++ct) {
            half8 bf = *(half8*)&sW[(kc * 8 + ct) * 64 + lane];
            acc[ct] = __builtin_amdgcn_mfma_f32_16x16x32_f16(af[kc], bf, acc[ct], 0, 0, 0);
        }
    }

    __syncthreads();

    _Float16* eb = (_Float16*)smem + wave * 16 * 136;   // 136 halfs = 272 B row stride
    float dv[4];
#pragma unroll
    for (int r = 0; r < 4; ++r) {
        int rr = row0 + quad * 4 + r;
        dv[r] = dinv[(rr < n) ? rr : (n - 1)];
    }
#pragma unroll
    for (int ct = 0; ct < 8; ++ct)
#pragma unroll
        for (int r = 0; r < 4; ++r)
            eb[(quad * 4 + r) * 136 + ct * 16 + l16] = (_Float16)(acc[ct][r] * dv[r]);

#pragma unroll
    for (int i = 0; i < 4; ++i) {
        int linear = i * 64 + lane;
        int r = linear >> 4, c = linear & 15;
        uint4 v = *(uint4*)((char*)eb + r * 272 + c * 16);
        int row = row0 + r;
        if (row < n) C[(size_t)row * 16 + c] = v;
    }
}

// ---------------- CSR aggregation + bias + ReLU + BN (+ optional classifier) ----------------
// (R8-verified structure, unchanged: 32 lanes/node, uint2 gathers, batch-8)

__device__ __forceinline__ void acc_row(float4& acc, uint2 q) {
    float2 f01 = __half22float2(*(__half2*)&q.x);
    float2 f23 = __half22float2(*(__half2*)&q.y);
    acc.x += f01.x; acc.y += f01.y; acc.z += f23.x; acc.w += f23.y;
}

template <bool FUSE_CLS>
__global__ __launch_bounds__(256) void k_aggregate(const uint2* __restrict__ Ah,
                                                   const int* __restrict__ offs,
                                                   const int* __restrict__ er,
                                                   const float* __restrict__ dinv,
                                                   const float* __restrict__ bias,
                                                   const float* __restrict__ g,
                                                   const float* __restrict__ be,
                                                   const float* __restrict__ rm,
                                                   const float* __restrict__ rv,
                                                   uint2* __restrict__ Hout,
                                                   const float* __restrict__ Wc,
                                                   const float* __restrict__ bc,
                                                   float* __restrict__ out, int n) {
    int lane = threadIdx.x & 31;
    int node = blockIdx.x * 8 + (threadIdx.x >> 5);
    if (node >= n) return;

    float4 acc = f4zero();
    acc_row(acc, Ah[(size_t)node * 32 + lane]);   // self loop (weight folds to dinv^2)

    int e0 = offs[node], e1 = offs[node + 1];
    for (int e = e0; e < e1; e += 8) {
        int4 ra = *(const int4*)(er + e);
        int4 rb = *(const int4*)(er + e + 4);
        uint2 v0 = Ah[(size_t)ra.x * 32 + lane];
        uint2 v1 = Ah[(size_t)ra.y * 32 + lane];
        uint2 v2 = Ah[(size_t)ra.z * 32 + lane];
        uint2 v3 = Ah[(size_t)ra.w * 32 + lane];
        uint2 v4 = Ah[(size_t)rb.x * 32 + lane];
        uint2 v5 = Ah[(size_t)rb.y * 32 + lane];
        uint2 v6 = Ah[(size_t)rb.z * 32 + lane];
        uint2 v7 = Ah[(size_t)rb.w * 32 + lane];
        acc_row(acc, v0); acc_row(acc, v1); acc_row(acc, v2); acc_row(acc, v3);
        acc_row(acc, v4); acc_row(acc, v5); acc_row(acc, v6); acc_row(acc, v7);
    }

    float di = dinv[node];
    acc.x *= di; acc.y *= di; acc.z *= di; acc.w *= di;

    float4 b4  = ((const float4*)bias)[lane];
    float4 g4  = ((const float4*)g)[lane];
    float4 be4 = ((const float4*)be)[lane];
    float4 rm4 = ((const float4*)rm)[lane];
    float4 rv4 = ((const float4*)rv)[lane];

    float4 o;
    float v;
    v = fmaxf(acc.x + b4.x, 0.f); o.x = (v - rm4.x) * rsqrtf(rv4.x + BN_EPS) * g4.x + be4.x;
    v = fmaxf(acc.y + b4.y, 0.f); o.y = (v - rm4.y) * rsqrtf(rv4.y + BN_EPS) * g4.y + be4.y;
    v = fmaxf(acc.z + b4.z, 0.f); o.z = (v - rm4.z) * rsqrtf(rv4.z + BN_EPS) * g4.z + be4.z;
    v = fmaxf(acc.w + b4.w, 0.f); o.w = (v - rm4.w) * rsqrtf(rv4.w + BN_EPS) * g4.w + be4.w;

    if (!FUSE_CLS) {
        __half2 p0 = __floats2half2_rn(o.x, o.y);
        __half2 p1 = __floats2half2_rn(o.z, o.w);
        uint2 u;
        u.x = *(unsigned int*)&p0;
        u.y = *(unsigned int*)&p1;
        Hout[(size_t)node * 32 + lane] = u;
    } else {
        const float4* Wv = (const float4*)Wc;
        float4 w01 = Wv[2 * lane];
        float4 w23 = Wv[2 * lane + 1];
        float p0 = o.x * w01.x + o.y * w01.z + o.z * w23.x + o.w * w23.z;
        float p1 = o.x * w01.y + o.y * w01.w + o.z * w23.y + o.w * w23.w;
#pragma unroll
        for (int d = 16; d >= 1; d >>= 1) {
            p0 += __shfl_down(p0, d, 32);
            p1 += __shfl_down(p1, d, 32);
        }
        if (lane == 0) {
            out[node * 2 + 0] = p0 + bc[0];
            out[node * 2 + 1] = p1 + bc[1];
        }
    }
}

// ---------------- launch ----------------

extern "C" void kernel_launch(void* const* d_in, const int* in_sizes, int n_in,
                              void* d_out, int out_size, void* d_ws, size_t ws_size,
                              hipStream_t stream) {
    const float* x   = (const float*)d_in[0];
    const int*   ei  = (const int*)d_in[1];
    const float* W1  = (const float*)d_in[2];
    const float* b1  = (const float*)d_in[3];
    const float* W2  = (const float*)d_in[4];
    const float* b2  = (const float*)d_in[5];
    const float* W3  = (const float*)d_in[6];
    const float* b3  = (const float*)d_in[7];
    const float* g1  = (const float*)d_in[8];
    const float* be1 = (const float*)d_in[9];
    const float* rm1 = (const float*)d_in[10];
    const float* rv1 = (const float*)d_in[11];
    const float* g2  = (const float*)d_in[12];
    const float* be2 = (const float*)d_in[13];
    const float* rm2 = (const float*)d_in[14];
    const float* rv2 = (const float*)d_in[15];
    const float* g3  = (const float*)d_in[16];
    const float* be3 = (const float*)d_in[17];
    const float* rm3 = (const float*)d_in[18];
    const float* rv3 = (const float*)d_in[19];
    const float* Wc  = (const float*)d_in[20];
    const float* bc  = (const float*)d_in[21];
    float* out = (float*)d_out;

    int n = in_sizes[0] / 128;
    int e = in_sizes[1] / 2;
    const int* src = ei;
    const int* dst = ei + e;

    char* ws = (char*)d_ws;
    size_t off = 0;
    auto alloc = [&](size_t bytes) -> char* {
        char* p = ws + off;
        off += (bytes + 255) & ~(size_t)255;
        return p;
    };
    int nA    = (e + CHUNK - 1) / CHUNK;
    int nbuck = (n + (1 << BBITS) - 1) >> BBITS;
    int tlen  = nbuck * nA;
    int erCap = e + 8 * n;

    char*      bufA     = (char*) alloc((size_t)(n + 1) * 256);   // GEMM out f16 [n+1][128]
    char*      bufH     = (char*) alloc((size_t)n * 256);         // H f16; prep scratch alias
    float*     dinv     = (float*)alloc((size_t)n * 4);
    int*       counts   = (int*)  alloc((size_t)n * 4);
    int*       offs     = (int*)  alloc((size_t)(n + 1) * 4);
    int*       localOff = (int*)  alloc((size_t)n * 4);
    int*       btot     = (int*)  alloc((size_t)(nbuck + 1) * 4);
    int*       bktBase  = (int*)  alloc((size_t)(nbuck + 1) * 4);
    int*       tableT   = (int*)  alloc((size_t)(tlen + 1) * 4);
    int*       parts    = (int*)  alloc(8192);
    int*       er       = (int*)  alloc((size_t)erCap * 4);
    _Float16*  pW       = (_Float16*)alloc(3 * 16384 * 2);
    (void)ws_size; (void)n_in; (void)out_size;

    // bed + brank alias bufH (dead until first aggregate; consumed by k_finalize)
    int2* bed   = (int2*)bufH;                       // e*8 = 12.8 MB
    int*  brank = (int*)(bufH + (size_t)e * 8);      // e*4 = 6.4 MB  (total 19.2 < 25.6 MB)

    int gN  = (n + 255) / 256;
    int nbT = (tlen + 1023) / 1024;

    k_pack_hist<<<24 + nA, 256, 0, stream>>>(W1, W2, W3, pW, dst, tableT, nA, nbuck, e);
    k_scan_block<<<nbT, 1024, 0, stream>>>(tableT, tableT, parts, tlen);
    k_scan_addp<<<(tlen + 255) / 256, 256, 0, stream>>>(tableT, parts, tlen);
    k_bucket_scatter<<<nA, 256, 0, stream>>>(src, dst, tableT, bed, nA, nbuck, e);
    k_bucket_rank<<<nbuck, 256, 0, stream>>>(bed, tableT, brank, counts, dinv, localOff,
                                             btot, nA, nbuck, n, e);
    k_scan_buckets<<<1, 1024, 0, stream>>>(btot, bktBase, nbuck);
    int gP = gN + (e / 2 + 255) / 256 + 1;
    k_finalize<<<gP, 256, 0, stream>>>(counts, localOff, bktBase, offs, er, bed, brank,
                                       (unsigned int*)(bufA + (size_t)n * 256), n, e, gN, nbuck);

    int gGemm = (n + 63) / 64;
    int gAgg  = (n + 7) / 8;

    k_gemm_mfma<true><<<gGemm, 256, 0, stream>>>(x, pW, dinv, (uint4*)bufA, n);
    k_aggregate<false><<<gAgg, 256, 0, stream>>>((const uint2*)bufA, offs, er, dinv,
                                                 b1, g1, be1, rm1, rv1, (uint2*)bufH,
                                                 nullptr, nullptr, nullptr, n);

    k_gemm_mfma<false><<<gGemm, 256, 0, stream>>>(bufH, pW + 16384, dinv, (uint4*)bufA, n);
    k_aggregate<false><<<gAgg, 256, 0, stream>>>((const uint2*)bufA, offs, er, dinv,
                                                 b2, g2, be2, rm2, rv2, (uint2*)bufH,
                                                 nullptr, nullptr, nullptr, n);

    k_gemm_mfma<false><<<gGemm, 256, 0, stream>>>(bufH, pW + 32768, dinv, (uint4*)bufA, n);
    k_aggregate<true><<<gAgg, 256, 0, stream>>>((const uint2*)bufA, offs, er, dinv,
                                                b3, g3, be3, rm3, rv3, nullptr,
                                                Wc, bc, out, n);
}